// Round 10
// baseline (2466.570 us; speedup 1.0000x reference)
//
#include <hip/hip_runtime.h>
#include <math.h>

typedef float  f32x4  __attribute__((ext_vector_type(4)));
typedef __bf16 bf16x8 __attribute__((ext_vector_type(8)));
typedef __bf16 bf16x4 __attribute__((ext_vector_type(4)));

#define DEV __device__ __forceinline__

DEV f32x4 mfma16(bf16x8 a, bf16x8 b, f32x4 c) {
    return __builtin_amdgcn_mfma_f32_16x16x32_bf16(a, b, c, 0, 0, 0);
}

DEV void async16(const void* g, void* l) {
    __builtin_amdgcn_global_load_lds((const __attribute__((address_space(1))) void*)g,
                                     (__attribute__((address_space(3))) void*)l, 16, 0, 0);
}

// ---------------------------------------------------------------- constants
constexpr int B_  = 8;
constexpr int S_  = 512;
constexpr int D_  = 1024;
constexpr int H_  = 16;
constexpr int FF_ = 4096;
constexpr int ROWS = B_ * S_;   // 4096

// ---------------------------------------------------------------- embed + LN -> bf16
__global__ __launch_bounds__(256)
void embed_ln_kernel(const int* __restrict__ ids, const int* __restrict__ lgs,
                     const float* __restrict__ fmask,
                     const float* __restrict__ wemb, const float* __restrict__ pemb,
                     const float* __restrict__ lemb,
                     const float* __restrict__ g, const float* __restrict__ bb,
                     __bf16* __restrict__ xb)
{
    __shared__ float2 red[4];
    const int row = blockIdx.x;
    const int s   = row & (S_ - 1);
    const int t   = threadIdx.x;
    const int lane = t & 63, w = t >> 6;
    const int id = ids[row], lg = lgs[row];

    float4 wv = *(const float4*)(wemb + ((size_t)id << 10) + t * 4);
    float4 pv = *(const float4*)(pemb + ((size_t)s  << 10) + t * 4);
    float4 lv = *(const float4*)(lemb + ((size_t)lg << 10) + t * 4);
    float a[4] = { wv.x + pv.x + lv.x, wv.y + pv.y + lv.y,
                   wv.z + pv.z + lv.z, wv.w + pv.w + lv.w };

    float sm = a[0] + a[1] + a[2] + a[3];
    float sq = a[0]*a[0] + a[1]*a[1] + a[2]*a[2] + a[3]*a[3];
#pragma unroll
    for (int o = 32; o > 0; o >>= 1) { sm += __shfl_down(sm, o); sq += __shfl_down(sq, o); }
    if (lane == 0) red[w] = make_float2(sm, sq);
    __syncthreads();
    float ts = red[0].x + red[1].x + red[2].x + red[3].x;
    float tq = red[0].y + red[1].y + red[2].y + red[3].y;
    float mean = ts * (1.0f / D_);
    float var  = tq * (1.0f / D_) - mean * mean;
    float rs   = rsqrtf(var + 1e-12f);
    float fm   = fmask[row];

    float4 gv = *(const float4*)(g  + t * 4);
    float4 bv = *(const float4*)(bb + t * 4);
    bf16x4 ob;
    ob[0] = (__bf16)(((a[0]-mean)*rs*gv.x + bv.x) * fm);
    ob[1] = (__bf16)(((a[1]-mean)*rs*gv.y + bv.y) * fm);
    ob[2] = (__bf16)(((a[2]-mean)*rs*gv.z + bv.z) * fm);
    ob[3] = (__bf16)(((a[3]-mean)*rs*gv.w + bv.w) * fm);
    *(bf16x4*)(xb + ((size_t)row << 10) + t * 4) = ob;
}

// ---------------- bf16 residual + NP bf16 partials + LN (+mask) -> bf16 (+fp32 out)
template<int NP>
__global__ __launch_bounds__(128)
void ln_resN_kernel(const __bf16* __restrict__ xres, const __bf16* __restrict__ yp,
                    const float* __restrict__ g, const float* __restrict__ bb,
                    const float* __restrict__ fmask,
                    __bf16* __restrict__ xb_out, float* __restrict__ fout)
{
    constexpr size_t MN = (size_t)ROWS * D_;
    __shared__ float2 red[2];
    const int row = blockIdx.x;
    const int t   = threadIdx.x;            // 0..127
    const int lane = t & 63, w = t >> 6;
    const size_t base = ((size_t)row << 10) + t * 8;

    bf16x8 xv = *(const bf16x8*)(xres + base);
    float a[8];
#pragma unroll
    for (int j = 0; j < 8; ++j) a[j] = (float)xv[j];
#pragma unroll
    for (int pslice = 0; pslice < NP; ++pslice) {
        bf16x8 yv = *(const bf16x8*)(yp + base + (size_t)pslice * MN);
#pragma unroll
        for (int j = 0; j < 8; ++j) a[j] += (float)yv[j];
    }

    float sm = 0.f, sq = 0.f;
#pragma unroll
    for (int j = 0; j < 8; ++j) { sm += a[j]; sq += a[j] * a[j]; }
#pragma unroll
    for (int o = 32; o > 0; o >>= 1) { sm += __shfl_down(sm, o); sq += __shfl_down(sq, o); }
    if (lane == 0) red[w] = make_float2(sm, sq);
    __syncthreads();
    float ts = red[0].x + red[1].x;
    float tq = red[0].y + red[1].y;
    float mean = ts * (1.0f / D_);
    float var  = tq * (1.0f / D_) - mean * mean;
    float rs   = rsqrtf(var + 1e-12f);
    float fm   = fmask ? fmask[row] : 1.0f;

    float4 gv0 = *(const float4*)(g  + t * 8);
    float4 gv1 = *(const float4*)(g  + t * 8 + 4);
    float4 bv0 = *(const float4*)(bb + t * 8);
    float4 bv1 = *(const float4*)(bb + t * 8 + 4);
    float gg[8] = { gv0.x, gv0.y, gv0.z, gv0.w, gv1.x, gv1.y, gv1.z, gv1.w };
    float bbv[8] = { bv0.x, bv0.y, bv0.z, bv0.w, bv1.x, bv1.y, bv1.z, bv1.w };

    float o[8];
    bf16x8 ob;
#pragma unroll
    for (int j = 0; j < 8; ++j) {
        o[j] = ((a[j] - mean) * rs * gg[j] + bbv[j]) * fm;
        ob[j] = (__bf16)o[j];
    }
    *(bf16x8*)(xb_out + base) = ob;
    if (fout) {
        *(float4*)(fout + base)     = make_float4(o[0], o[1], o[2], o[3]);
        *(float4*)(fout + base + 4) = make_float4(o[4], o[5], o[6], o[7]);
    }
}

// ----------- upfront ALL-LAYER weight convert fp32[K][N] -> bf16[N][K] (1 dispatch)
// v4: 4x k-coarsened blocks (64n x 256k). Reads float4; LDS transpose per 64x64
// sub-tile (v3's verified low-conflict swizzle); outputs stashed in regs; each
// n-row written as 4x16B covering a contiguous 512B span (DRAM-friendly bursts).
__global__ __launch_bounds__(256)
void conv_all_kernel(const float* __restrict__ Wq, const float* __restrict__ Wk,
                     const float* __restrict__ Wv, const float* __restrict__ Wo,
                     const float* __restrict__ W1, const float* __restrict__ W2,
                     __bf16* __restrict__ qkvT, __bf16* __restrict__ woT,
                     __bf16* __restrict__ w1T, __bf16* __restrict__ w2T)
{
    __shared__ unsigned int tile32[64 * 34];   // [n][k/2], stride 34 words
    const int id = blockIdx.x;
    const int l  = id / 768;
    int t = id - l * 768;
    const size_t woff = (size_t)l * D_ * D_;
    const size_t foff = (size_t)l * D_ * FF_;
    const float* src; __bf16* dst; int K, N;
    if (t < 256) {
        const int m = t >> 6; t &= 63; K = 1024; N = 1024;
        src = ((m == 0) ? Wq : (m == 1) ? Wk : (m == 2) ? Wv : Wo) + woff;
        dst = (m == 3) ? (woT + woff)
                       : (qkvT + (size_t)l * 3 * D_ * D_ + (size_t)m * D_ * D_);
    } else if (t < 512) {
        t -= 256; K = 1024; N = 4096; src = W1 + foff; dst = w1T + foff;
    } else {
        t -= 512; K = 4096; N = 1024; src = W2 + foff; dst = w2T + foff;
    }
    const int ksup = K >> 8;                 // 256-row k-supertiles
    const int tk = t % ksup, tn = t / ksup;
    const int k0s = tk << 8, n0t = tn << 6;
    const int tt = threadIdx.x;

    const int kp = tt >> 4;          // 0..15 (k-pair)
    const int nq = tt & 15;          // 0..15 (n quad)
    const int swzw = (nq >> 2) << 2;
    const int nr = tt >> 3;          // 0..31
    const int kc = tt & 7;           // 0..7

    bf16x8 ob[2][4];
#pragma unroll
    for (int i4 = 0; i4 < 4; ++i4) {
        const int k0t = k0s + i4 * 64;
#pragma unroll
        for (int i = 0; i < 2; ++i) {
            const int k0 = i * 32 + kp * 2;
            const float4 r0 = *(const float4*)(src + (size_t)(k0t + k0)     * N + n0t + nq * 4);
            const float4 r1 = *(const float4*)(src + (size_t)(k0t + k0 + 1) * N + n0t + nq * 4);
            const int j = (i * 16 + kp) ^ swzw;
            const float lo[4] = { r0.x, r0.y, r0.z, r0.w };
            const float hi[4] = { r1.x, r1.y, r1.z, r1.w };
#pragma unroll
            for (int c = 0; c < 4; ++c) {
                const int n = nq * 4 + c;
                union { unsigned int u; __bf16 b[2]; } pk;
                pk.b[0] = (__bf16)lo[c];
                pk.b[1] = (__bf16)hi[c];
                tile32[n * 34 + j] = pk.u;
            }
        }
        __syncthreads();
#pragma unroll
        for (int pp = 0; pp < 2; ++pp) {
            const int n = pp * 32 + nr;
            const int jb = (kc * 4) ^ ((n >> 4) << 2);
            const unsigned int* tp = tile32 + n * 34 + jb;
            union { unsigned int u[4]; bf16x8 v; } o;
            o.u[0] = tp[0]; o.u[1] = tp[1]; o.u[2] = tp[2]; o.u[3] = tp[3];
            ob[pp][i4] = o.v;
        }
        __syncthreads();
    }
#pragma unroll
    for (int pp = 0; pp < 2; ++pp) {
        const int n = pp * 32 + nr;
        __bf16* drow = dst + (size_t)(n0t + n) * K + k0s + kc * 8;
#pragma unroll
        for (int i4 = 0; i4 < 4; ++i4)
            *(bf16x8*)(drow + i4 * 64) = ob[pp][i4];
    }
}

// ================================================================ 256x256 8-phase GEMM
// (schedule unchanged — verified)
// EPI 0: QKV (q*0.125 bf16; k bf16; V -> TRANSPOSED vT[b][h][64][512])
// EPI 2: GELU(sigmoid form)->bf16.  EPI 3: split-K bf16 partials at oP + slice*M*N.
template<int EPI>
__global__ __launch_bounds__(512, 2)
void gemm256_kernel(const __bf16* __restrict__ A, const __bf16* __restrict__ Bt,
                    const float* __restrict__ b0, const float* __restrict__ b1,
                    const float* __restrict__ b2,
                    __bf16* __restrict__ o0, __bf16* __restrict__ o1,
                    __bf16* __restrict__ o2, __bf16* __restrict__ oP,
                    int M, int N, int K, int Kloc, int nTn, int tiles)
{
    __shared__ __bf16 lds[65536];
    const int tid  = threadIdx.x;
    const int lane = tid & 63;
    const int w    = tid >> 6;
    const int wr   = w >> 2, wc = w & 3;

    const int nwg = gridDim.x, bid = blockIdx.x;
    const int cpx = nwg >> 3;
    const int bswz = (bid & 7) * cpx + (bid >> 3);
    const int slice = bswz / tiles;
    const int tile  = bswz % tiles;
    const int bm = tile / nTn, bn = tile % nTn;
    const int m0 = bm << 8, n0 = bn << 8;
    const int ks = slice * Kloc;

    const int rrT = tid >> 3;
    const size_t swzK  = (size_t)(((tid & 7) ^ (rrT & 7)) * 8);
    const size_t aoff0 = (size_t)rrT * K + swzK;
    const size_t boff0 = (size_t)((rrT >> 5) * 64 + (rrT & 31)) * K + swzK;
    const size_t boff1 = (size_t)(((rrT >> 5) + 2) * 64 + (rrT & 31)) * K + swzK;
    const int wub = w * 512;

    const int aread = (wr * 64 + (lane & 15)) * 64;
    const int bread = (wc * 32 + (lane & 15)) * 64;
    const int csw0 = ((      (lane >> 4) * 16) ^ ((lane & 7) << 4)) >> 1;
    const int csw1 = ((64 +  (lane >> 4) * 16) ^ ((lane & 7) << 4)) >> 1;

    f32x4 acc[8][4] = {};
    bf16x8 a_[4][2], b_[2][2];

#define ST_A(p,h,kt) do {                                                     \
    const size_t gb = (size_t)(m0 + (h) * 64) * K + (kt);                     \
    async16(A + gb + aoff0,                  lds + ((p)*2+(h))*8192 + wub);   \
    async16(A + gb + (size_t)128*K + aoff0,  lds + ((p)*2+(h))*8192 + 4096 + wub); \
} while (0)
#define ST_B(p,h,kt) do {                                                     \
    const size_t gb = (size_t)(n0 + (h) * 32) * K + (kt);                     \
    async16(Bt + gb + boff0, lds + 32768 + ((p)*2+(h))*8192 + wub);           \
    async16(Bt + gb + boff1, lds + 32768 + ((p)*2+(h))*8192 + 4096 + wub);    \
} while (0)
#define DS_A(p,h) do {                                                        \
    const __bf16* base_ = lds + ((p)*2+(h))*8192 + aread;                     \
    _Pragma("unroll") for (int m_ = 0; m_ < 4; ++m_) {                        \
        a_[m_][0] = *(const bf16x8*)(base_ + m_*1024 + csw0);                 \
        a_[m_][1] = *(const bf16x8*)(base_ + m_*1024 + csw1);                 \
    }                                                                         \
} while (0)
#define DS_B(p,h) do {                                                        \
    const __bf16* base_ = lds + 32768 + ((p)*2+(h))*8192 + bread;             \
    _Pragma("unroll") for (int n_ = 0; n_ < 2; ++n_) {                        \
        b_[n_][0] = *(const bf16x8*)(base_ + n_*1024 + csw0);                 \
        b_[n_][1] = *(const bf16x8*)(base_ + n_*1024 + csw1);                 \
    }                                                                         \
} while (0)
#define MM(mb,nb) do {                                                        \
    _Pragma("unroll") for (int m_ = 0; m_ < 4; ++m_)                          \
    _Pragma("unroll") for (int n_ = 0; n_ < 2; ++n_)                          \
    _Pragma("unroll") for (int k_ = 0; k_ < 2; ++k_)                          \
        acc[(mb)+m_][(nb)+n_] = mfma16(a_[m_][k_], b_[n_][k_], acc[(mb)+m_][(nb)+n_]); \
} while (0)
#define SYNC do { __builtin_amdgcn_s_barrier();                               \
    asm volatile("s_waitcnt lgkmcnt(0)" ::: "memory");                        \
    __builtin_amdgcn_s_setprio(1); } while (0)
#define PEND do { __builtin_amdgcn_s_setprio(0);                              \
    __builtin_amdgcn_s_barrier(); } while (0)

    ST_A(0,0, ks);      ST_B(0,1, ks);      ST_A(0,1, ks);      ST_B(0,0, ks);
    ST_A(1,0, ks + 64); ST_B(1,1, ks + 64); ST_A(1,1, ks + 64);
    asm volatile("s_waitcnt vmcnt(6)" ::: "memory");
    __builtin_amdgcn_s_barrier();

    const int nIter = Kloc >> 7;
    for (int i = 0; i < nIter; ++i) {
        const bool nl = (i != nIter - 1);
        const int kt1 = ks + (2*i+1) * 64;
        const int kt2 = ks + (2*i+2) * 64;
        const int kt3 = kt2 + 64;
        DS_A(0,0); DS_B(0,0); ST_B(1,0,kt1);
        SYNC; MM(0,0); PEND;
        DS_B(0,1); if (nl) ST_A(0,0,kt2);
        SYNC; MM(0,2); PEND;
        DS_A(0,1); if (nl) ST_B(0,1,kt2);
        SYNC; MM(4,2); PEND;
        DS_B(0,0); if (nl) ST_A(0,1,kt2);
        SYNC; MM(4,0);
        __builtin_amdgcn_s_setprio(0);
        if (nl) asm volatile("s_waitcnt vmcnt(6)" ::: "memory");
        else    asm volatile("s_waitcnt vmcnt(0)" ::: "memory");
        __builtin_amdgcn_s_barrier();
        DS_A(1,0); DS_B(1,0); if (nl) ST_B(0,0,kt2);
        SYNC; MM(0,0); PEND;
        DS_B(1,1); if (nl) ST_A(1,0,kt3);
        SYNC; MM(0,2); PEND;
        DS_A(1,1); if (nl) ST_B(1,1,kt3);
        SYNC; MM(4,2); PEND;
        DS_B(1,0); if (nl) ST_A(1,1,kt3);
        SYNC; MM(4,0);
        __builtin_amdgcn_s_setprio(0);
        if (nl) asm volatile("s_waitcnt vmcnt(6)" ::: "memory");
        __builtin_amdgcn_s_barrier();
    }
#undef ST_A
#undef ST_B
#undef DS_A
#undef DS_B
#undef MM
#undef SYNC
#undef PEND

    const int mrow = m0 + wr * 128 + (lane >> 4) * 4;
    const int ncol = n0 + wc * 64 + (lane & 15);
    if (EPI == 0) {
        const int sel = n0 >> 10;
        const int nc = ncol & 1023;
        if (sel < 2) {
            __bf16* out = (sel == 0) ? o0 : o1;
            const float* bp = (sel == 0) ? b0 : b1;
            const float scl = (sel == 0) ? 0.125f : 1.0f;
#pragma unroll
            for (int ni = 0; ni < 4; ++ni) {
                const float bvv = bp[nc + ni * 16];
#pragma unroll
                for (int mi = 0; mi < 8; ++mi)
#pragma unroll
                    for (int r = 0; r < 4; ++r)
                        out[(size_t)(mrow + mi * 16 + r) * D_ + nc + ni * 16] =
                            (__bf16)((acc[mi][ni][r] + bvv) * scl);
            }
        } else {
#pragma unroll
            for (int ni = 0; ni < 4; ++ni) {
                const int dhf = nc + ni * 16;
                const float bvv = b2[dhf];
                const int hh = dhf >> 6, dh = dhf & 63;
#pragma unroll
                for (int mi = 0; mi < 8; ++mi) {
                    const int gm0 = mrow + mi * 16;
                    const int bb_ = gm0 >> 9, s0 = gm0 & 511;
                    bf16x4 pk;
#pragma unroll
                    for (int r = 0; r < 4; ++r) pk[r] = (__bf16)(acc[mi][ni][r] + bvv);
                    *(bf16x4*)(o2 + ((size_t)((bb_ * 16 + hh) * 64 + dh) << 9) + s0) = pk;
                }
            }
        }
    } else if (EPI == 2) {
#pragma unroll
        for (int ni = 0; ni < 4; ++ni) {
            const float bvv = b0[ncol + ni * 16];
#pragma unroll
            for (int mi = 0; mi < 8; ++mi)
#pragma unroll
                for (int r = 0; r < 4; ++r) {
                    float v = acc[mi][ni][r] + bvv;
                    float u2 = 1.5957691216f * v * (1.0f + 0.044715f * v * v);
                    float ge = v / (1.0f + __expf(-u2));
                    o0[(size_t)(mrow + mi * 16 + r) * N + ncol + ni * 16] = (__bf16)ge;
                }
        }
    } else {
        __bf16* Y = oP + (size_t)slice * M * N;
#pragma unroll
        for (int ni = 0; ni < 4; ++ni) {
            const float bvv = (slice == 0) ? b0[ncol + ni * 16] : 0.0f;
#pragma unroll
            for (int mi = 0; mi < 8; ++mi)
#pragma unroll
                for (int r = 0; r < 4; ++r)
                    Y[(size_t)(mrow + mi * 16 + r) * N + ncol + ni * 16] =
                        (__bf16)(acc[mi][ni][r] + bvv);
        }
    }
}

// ---------------------------------------------------------------- attention v3.1
// 128 q-rows/block, 8 waves; K + V^T staged once; mask folded from global.
__global__ __launch_bounds__(512, 1)
void attn_kernel(const __bf16* __restrict__ q, const __bf16* __restrict__ k,
                 const __bf16* __restrict__ vT, const float* __restrict__ fmask,
                 __bf16* __restrict__ ctx)
{
    __shared__ __bf16 Ks[512 * 64];       // 64 KB; chunk-P overlays after QK^T
    __shared__ __bf16 Vt[64 * 512];       // 64 KB, slot-XOR-swizzled content
    const int bid = blockIdx.x;
    const int qt = bid & 3, h = (bid >> 2) & 15, b = bid >> 6;
    const int tid = threadIdx.x, lane = tid & 63, w = tid >> 6;
    const int g = lane >> 4, q15 = lane & 15, r7 = lane & 7;

    const __bf16* kbase  = k  + ((size_t)b * S_) * D_ + h * 64;
    const __bf16* vTbase = vT + ((size_t)((b * 16 + h) * 64) << 9);
    const float*  fmb    = fmask + b * S_;
    char* kl = (char*)Ks + (tid & ~63) * 16;
    char* vl = (char*)Vt + (tid & ~63) * 16;
    const int srow  = tid >> 3;
    const int sslot = (tid & 7) ^ (srow & 7);

#pragma unroll
    for (int i = 0; i < 8; ++i) {
        const int s = i * 64 + srow;
        async16(kbase + (size_t)s * D_ + sslot * 8, kl + i * 8192);
    }
#pragma unroll
    for (int i = 0; i < 8; ++i) {
        const int d = i * 8 + w;
        async16(vTbase + ((size_t)d << 9) + (((tid & 63) ^ (d & 7)) << 3), vl + i * 8192);
    }

    const __bf16* qbase = q + ((size_t)b * S_ + qt * 128 + w * 16) * D_ + h * 64;
    const bf16x8 qf0 = *(const bf16x8*)(qbase + (size_t)q15 * D_ + g * 8);
    const bf16x8 qf1 = *(const bf16x8*)(qbase + (size_t)q15 * D_ + 32 + g * 8);

    f32x4 sc[32];
#pragma unroll
    for (int i = 0; i < 32; ++i) { sc[i][0] = 0.f; sc[i][1] = 0.f; sc[i][2] = 0.f; sc[i][3] = 0.f; }

    __syncthreads();          // B1: K + V resident
#pragma unroll
    for (int nf = 0; nf < 32; ++nf) {
        const __bf16* kr = Ks + (nf * 16 + q15) * 64;
        const bf16x8 kf0 = *(const bf16x8*)(kr + ((g ^ r7) << 3));
        const bf16x8 kf1 = *(const bf16x8*)(kr + (((g + 4) ^ r7) << 3));
        sc[nf] = mfma16(kf0, qf0, sc[nf]);
        sc[nf] = mfma16(kf1, qf1, sc[nf]);
    }

    // ---- mask (from global, L1-broadcast) + softmax (per-lane)
    float mx = -3e38f;
#pragma unroll
    for (int i = 0; i < 32; ++i) {
        const float4 fm4 = *(const float4*)(fmb + i * 16 + 4 * g);
        sc[i][0] += (fm4.x - 1.0f) * 1e30f;
        sc[i][1] += (fm4.y - 1.0f) * 1e30f;
        sc[i][2] += (fm4.z - 1.0f) * 1e30f;
        sc[i][3] += (fm4.w - 1.0f) * 1e30f;
        mx = fmaxf(mx, fmaxf(fmaxf(sc[i][0], sc[i][1]), fmaxf(sc[i][2], sc[i][3])));
    }
    mx = fmaxf(mx, __shfl_xor(mx, 16));
    mx = fmaxf(mx, __shfl_xor(mx, 32));
    float sum = 0.f;
#pragma unroll
    for (int i = 0; i < 32; ++i)
#pragma unroll
        for (int r = 0; r < 4; ++r) { float pp = __expf(sc[i][r] - mx); sc[i][r] = pp; sum += pp; }
    sum += __shfl_xor(sum, 16);
    sum += __shfl_xor(sum, 32);
    const float inv = 1.0f / sum;

    __bf16* P = Ks + w * 4096;
    f32x4 co[4] = {};
#define WR_P(c) do { _Pragma("unroll") for (int i_ = 0; i_ < 16; ++i_) {      \
        bf16x4 pk;                                                            \
        _Pragma("unroll") for (int r = 0; r < 4; ++r) pk[r] = (__bf16)sc[(c)*16+i_][r]; \
        *(bf16x4*)(P + q15 * 256 + ((i_ * 16 + 4 * g) ^ (8 * r7))) = pk; } } while (0)
#define PV(c) do { _Pragma("unroll") for (int kt = 0; kt < 8; ++kt) {         \
        const bf16x8 pf = *(const bf16x8*)(P + q15 * 256 + ((kt * 32 + 8 * g) ^ (8 * r7))); \
        _Pragma("unroll") for (int nf = 0; nf < 4; ++nf) {                    \
            const int d_ = nf * 16 + q15;                                     \
            const bf16x8 vf = *(const bf16x8*)(Vt + d_ * 512 +                \
                (((c) * 256 + kt * 32 + 8 * g) ^ (8 * r7)));                  \
            co[nf] = mfma16(vf, pf, co[nf]); } } } while (0)

    __syncthreads();          // B2: QK^T reads of Ks done
    WR_P(0);
    __syncthreads();          // B3: P c0 visible
    PV(0);
    __syncthreads();          // B4: PV c0 P-reads done
    WR_P(1);
    __syncthreads();          // B5: P c1 visible
    PV(1);
#undef WR_P
#undef PV

    __bf16* cb = ctx + ((size_t)b * S_ + qt * 128 + w * 16 + q15) * D_ + h * 64;
#pragma unroll
    for (int nf = 0; nf < 4; ++nf) {
        bf16x4 o4;
#pragma unroll
        for (int r = 0; r < 4; ++r) o4[r] = (__bf16)(co[nf][r] * inv);
        *(bf16x4*)(cb + nf * 16 + 4 * g) = o4;
    }
}

// ---------------------------------------------------------------- launcher
extern "C" void kernel_launch(void* const* d_in, const int* in_sizes, int n_in,
                              void* d_out, int out_size, void* d_ws, size_t ws_size,
                              hipStream_t stream)
{
    (void)in_sizes; (void)n_in; (void)out_size; (void)ws_size;
    const int*   ids   = (const int*)d_in[0];
    const int*   lgs   = (const int*)d_in[1];
    const float* amask = (const float*)d_in[2];
    const float* wemb  = (const float*)d_in[3];
    const float* pemb  = (const float*)d_in[4];
    const float* lemb  = (const float*)d_in[5];
    const float* lng   = (const float*)d_in[6];
    const float* lnbv  = (const float*)d_in[7];
    const float* Wq = (const float*)d_in[8];  const float* bq = (const float*)d_in[9];
    const float* Wk = (const float*)d_in[10]; const float* bk = (const float*)d_in[11];
    const float* Wv = (const float*)d_in[12]; const float* bv = (const float*)d_in[13];
    const float* Wo = (const float*)d_in[14]; const float* bo = (const float*)d_in[15];
    const float* g1 = (const float*)d_in[16]; const float* be1 = (const float*)d_in[17];
    const float* W1 = (const float*)d_in[18]; const float* b1 = (const float*)d_in[19];
    const float* W2 = (const float*)d_in[20]; const float* b2 = (const float*)d_in[21];
    const float* g2 = (const float*)d_in[22]; const float* be2 = (const float*)d_in[23];

    char* p = (char*)d_ws;
    auto take = [&](size_t n) { char* r = p; p += (n + 255) & ~(size_t)255; return r; };
    __bf16* xb    = (__bf16*)take((size_t)ROWS * D_ * 2);
    __bf16* qb    = (__bf16*)take((size_t)ROWS * D_ * 2);
    __bf16* kb    = (__bf16*)take((size_t)ROWS * D_ * 2);
    __bf16* vT    = (__bf16*)take((size_t)ROWS * D_ * 2);   // [B][H][64][512]
    __bf16* cxb   = (__bf16*)take((size_t)ROWS * D_ * 2);
    __bf16* hb    = (__bf16*)take((size_t)ROWS * FF_ * 2);
    __bf16* ybp   = (__bf16*)take((size_t)4 * ROWS * D_ * 2);  // bf16 partials (4 slices)
    __bf16* wqkvT = (__bf16*)take((size_t)12 * 3 * D_ * D_ * 2);
    __bf16* woT   = (__bf16*)take((size_t)12 * D_ * D_ * 2);
    __bf16* w1T   = (__bf16*)take((size_t)12 * D_ * FF_ * 2);
    __bf16* w2T   = (__bf16*)take((size_t)12 * FF_ * D_ * 2);

    const int gQKV = (ROWS / 256) * (3 * D_ / 256);   // 192
    const int gF1  = (ROWS / 256) * (FF_ / 256);      // 256
    const int gF2  = 4 * (ROWS / 256) * (D_ / 256);   // 256 (split-K=4, Kloc=1024)
    const int gWo  = 4 * (ROWS / 256) * (D_ / 256);   // 256 (split-K=4, Kloc=256)

    conv_all_kernel<<<12 * 768, 256, 0, stream>>>(Wq, Wk, Wv, Wo, W1, W2,
                                                  wqkvT, woT, w1T, w2T);

    embed_ln_kernel<<<ROWS, 256, 0, stream>>>(ids, lgs, amask, wemb, pemb, lemb, lng, lnbv, xb);

    for (int l = 0; l < 12; ++l) {
        __bf16* wqkvL = wqkvT + (size_t)l * 3 * D_ * D_;
        __bf16* woL   = woT   + (size_t)l * D_ * D_;
        __bf16* w1L   = w1T   + (size_t)l * D_ * FF_;
        __bf16* w2L   = w2T   + (size_t)l * FF_ * D_;

        gemm256_kernel<0><<<gQKV, 512, 0, stream>>>(xb, wqkvL, bq + l * D_, bk + l * D_, bv + l * D_,
                                                    qb, kb, vT, nullptr,
                                                    ROWS, 3 * D_, D_, D_, 12, gQKV);

        attn_kernel<<<B_ * H_ * (S_ / 128), 512, 0, stream>>>(qb, kb, vT, amask, cxb);

        gemm256_kernel<3><<<gWo, 512, 0, stream>>>(cxb, woL, bo + l * D_, nullptr, nullptr,
                                                   nullptr, nullptr, nullptr, ybp,
                                                   ROWS, D_, D_, D_ / 4, 4, 64);
        ln_resN_kernel<4><<<ROWS, 128, 0, stream>>>(xb, ybp, g1 + l * D_, be1 + l * D_,
                                                    nullptr, xb, nullptr);

        gemm256_kernel<2><<<gF1, 512, 0, stream>>>(xb, w1L, b1 + l * FF_, nullptr, nullptr,
                                                   hb, nullptr, nullptr, nullptr,
                                                   ROWS, FF_, D_, D_, 16, gF1);
        gemm256_kernel<3><<<gF2, 512, 0, stream>>>(hb, w2L, b2 + l * D_, nullptr, nullptr,
                                                   nullptr, nullptr, nullptr, ybp,
                                                   ROWS, D_, FF_, D_, 4, 64);

        float* dst = (l == 11) ? (float*)d_out : nullptr;
        ln_resN_kernel<4><<<ROWS, 128, 0, stream>>>(xb, ybp, g2 + l * D_, be2 + l * D_,
                                                    amask, xb, dst);
    }
}